// Round 4
// baseline (593.983 us; speedup 1.0000x reference)
//
#include <hip/hip_runtime.h>

typedef unsigned short u16;
typedef __bf16 bf16x8 __attribute__((ext_vector_type(8)));
typedef u16 u16x8 __attribute__((ext_vector_type(8)));
typedef float f32x4 __attribute__((ext_vector_type(4)));

#define S_LEN 2048
#define H_LEN 1024

__device__ __forceinline__ u16 f2b(float f) {
  unsigned u = __float_as_uint(f);
  return (u16)((u + 0x7FFFu + ((u >> 16) & 1u)) >> 16);  // RNE
}
__device__ __forceinline__ float b2f(u16 h) { return __uint_as_float(((unsigned)h) << 16); }

#define GLOAD16(gp, lp)                                   \
  __builtin_amdgcn_global_load_lds(                       \
      (__attribute__((address_space(1))) void*)(gp),      \
      (__attribute__((address_space(3))) void*)(lp), 16, 0, 0)

#define FENCE() asm volatile("" ::: "memory")
#define PBAR()                           \
  do {                                   \
    FENCE();                             \
    __builtin_amdgcn_s_barrier();        \
    FENCE();                             \
  } while (0)
#define WAIT_LGKM0()                                        \
  do {                                                      \
    asm volatile("s_waitcnt lgkmcnt(0)" ::: "memory");      \
    __builtin_amdgcn_sched_barrier(0);                      \
  } while (0)
#define WAIT_VM(n) asm volatile("s_waitcnt vmcnt(" #n ")" ::: "memory")

__device__ __forceinline__ f32x4 MM(bf16x8 a, bf16x8 b, f32x4 c) {
  return __builtin_amdgcn_mfma_f32_16x16x32_bf16(a, b, c, 0, 0, 0);
}

// ---------------- prep: casts, bias pack, relbits pack, zero d1+denom --------
__global__ __launch_bounds__(256) void prep_kernel(
    const float* __restrict__ X, const float* __restrict__ Wq,
    const float* __restrict__ Wk, const float* __restrict__ Wv,
    const float* __restrict__ bq, const float* __restrict__ bk,
    const float* __restrict__ bv, const float* __restrict__ dist,
    const int* __restrict__ rel,
    u16* __restrict__ Xbf, u16* __restrict__ Wbf, float* __restrict__ b_all,
    u16* __restrict__ de1, unsigned* __restrict__ bits, float* __restrict__ d1) {
  size_t tid = (size_t)blockIdx.x * blockDim.x + threadIdx.x;
  size_t nth = (size_t)gridDim.x * blockDim.x;
  for (size_t i = tid; i < 4194304u; i += nth) {  // X: 16.7M floats / 4
    float4 v = ((const float4*)X)[i];
    ushort4 o; o.x = f2b(v.x); o.y = f2b(v.y); o.z = f2b(v.z); o.w = f2b(v.w);
    ((ushort4*)Xbf)[i] = o;
  }
  for (size_t i = tid; i < 786432u; i += nth) {  // Wq|Wk|Wv
    int which = (int)(i >> 18);
    size_t off = i & 262143u;
    const float4* src = (const float4*)(which == 0 ? Wq : (which == 1 ? Wk : Wv));
    float4 v = src[off];
    ushort4 o; o.x = f2b(v.x); o.y = f2b(v.y); o.z = f2b(v.z); o.w = f2b(v.w);
    ((ushort4*)Wbf)[i] = o;
  }
  // relbits: 8*2048*2048 int32 / 32 = 1048576 words, 32 elems per iter
  const int4* r4 = (const int4*)rel;
  for (size_t wi = tid; wi < 1048576u; wi += nth) {
    const int4* s = r4 + wi * 8;
    unsigned m = 0;
#pragma unroll
    for (int u = 0; u < 8; ++u) {
      int4 v = s[u];
      m |= (unsigned)(v.x == 1) << (u * 4 + 0);
      m |= (unsigned)(v.y == 1) << (u * 4 + 1);
      m |= (unsigned)(v.z == 1) << (u * 4 + 2);
      m |= (unsigned)(v.w == 1) << (u * 4 + 3);
    }
    bits[wi] = m;
  }
  for (size_t i = tid; i < 256u; i += nth) {  // dist_emb row 1
    float4 v = ((const float4*)(dist + H_LEN))[i];
    ushort4 o; o.x = f2b(v.x); o.y = f2b(v.y); o.z = f2b(v.z); o.w = f2b(v.w);
    ((ushort4*)de1)[i] = o;
  }
  for (size_t i = tid; i < 3072u; i += nth)
    b_all[i] = (i < 1024) ? bq[i] : (i < 2048 ? bk[i - 1024] : bv[i - 2048]);
  for (size_t i = tid; i < 32768u; i += nth) d1[i] = 0.f;  // d1[16384] + denom[16384]
}

// ---------------- 256x256 NT-GEMM, BK=64, 4-phase fine-interleaved K-loop ----
struct GArgs {
  const u16* A; const u16* B;
  long long sA, sB;
  int ldA, ldB, K;
  u16 *Qo, *Ko, *Vo; const float* b_all; const u16* de1; float* d1;       // EPI 0
  const unsigned* relbits; const float* mask; u16* P; float* denom;       // EPI 1
  float* outp;                                                            // EPI 2
};

template <int EPI>
__global__ __launch_bounds__(512, 2) void gemm256(GArgs g) {
  // XCD-bijective block swizzles (grids flattened to 1D, size % 8 == 0).
  int bx, by, bz;
  {
    const int lin = blockIdx.x;
    if constexpr (EPI == 0) {        // 768 blocks: 96/XCD, n fastest within band
      const int wg = (lin & 7) * 96 + (lin >> 3);
      by = wg / 12; bx = wg % 12; bz = 0;
    } else if constexpr (EPI == 1) { // 512 blocks: one batch (64 blocks) per XCD
      const int wg = (lin & 7) * 64 + (lin >> 3);
      bz = wg >> 6; by = (wg >> 3) & 7; bx = wg & 7;
    } else {                         // 256 blocks: 32/XCD (one batch per XCD)
      const int wg = (lin & 7) * 32 + (lin >> 3);
      bz = wg >> 5; by = (wg >> 2) & 7; bx = wg & 3;
    }
  }
  const u16* Abase = g.A + (size_t)bz * g.sA;
  const u16* Bbase = g.B + (size_t)bz * g.sB;
  const int m0 = by * 256, n0 = bx * 256;

  __shared__ u16 smem[65536];  // 128 KiB: [buf0: A 32K|B 32K][buf1: A 32K|B 32K]

  const int tid = threadIdx.x;
  const int lane = tid & 63, w = tid >> 6;
  const int wm = w >> 2, wn = w & 3;          // 2 x 4 waves, wave tile 128 x 64
  const int l15 = lane & 15, quad = lane >> 4;

  f32x4 acc[8][4];
  const f32x4 zero = {0.f, 0.f, 0.f, 0.f};
#pragma unroll
  for (int a = 0; a < 8; ++a)
#pragma unroll
    for (int b = 0; b < 4; ++b) acc[a][b] = zero;

  // staging: LDS written linearly; global SOURCE pre-swizzled with the same XOR
  // used on ds_read (both-sides-or-neither rule)
  const u16* gA[4]; const u16* gB[4]; int qoff[4];
#pragma unroll
  for (int r = 0; r < 4; ++r) {
    const int q = r * 512 + tid;        // 16B-chunk id in [0,2048)
    const int row = q >> 3, ch = q & 7;
    const int chS = ch ^ (row & 7);
    gA[r] = Abase + (size_t)(m0 + row) * g.ldA + chS * 8;
    gB[r] = Bbase + (size_t)(n0 + row) * g.ldB + chS * 8;
    qoff[r] = q * 8;                    // u16 offset in tile
  }

  const int NT = g.K >> 6;

  // stage pair 'pr' (2 gloads) of K-tile 'tile': pr 0-1 = A rows, pr 2-3 = B rows
  auto stage2 = [&](int tile, int pr) {
    if (tile >= NT) return;
    const int boff2 = (tile & 1) << 15;
    const int kt = tile << 6;
    if (pr < 2) {
      GLOAD16(gA[2 * pr] + kt,     &smem[boff2 + qoff[2 * pr]]);
      GLOAD16(gA[2 * pr + 1] + kt, &smem[boff2 + qoff[2 * pr + 1]]);
    } else {
      const int r = 2 * (pr - 2);
      GLOAD16(gB[r] + kt,     &smem[boff2 + 16384 + qoff[r]]);
      GLOAD16(gB[r + 1] + kt, &smem[boff2 + 16384 + qoff[r + 1]]);
    }
  };

  // prologue: tile 0 fully staged + tile 1 pair0 in flight; wait leaves 2 loads
  stage2(0, 0); stage2(0, 1); stage2(0, 2); stage2(0, 3);
  stage2(1, 0);
  if (1 < NT) { WAIT_VM(2); } else { WAIT_VM(0); }
  PBAR();

  bf16x8 af0[4][2], af1[4][2], bf0[2][2], bf1[2][2];

  for (int t = 0; t < NT; ++t) {
    const int boff = (t & 1) << 15;
    const u16* Ab = smem + boff;
    const u16* Bb = smem + boff + 16384;

    // ---- phase 0: read af0(8) + bf0(4); stage (t+1, pair1); MFMA Q00 -------
#pragma unroll
    for (int mt = 0; mt < 4; ++mt) {
      const int row = wm * 128 + mt * 16 + l15;
      const int base = row * 64, rx = row & 7;
      af0[mt][0] = *(const bf16x8*)&Ab[base + ((quad ^ rx) << 3)];
      af0[mt][1] = *(const bf16x8*)&Ab[base + (((quad + 4) ^ rx) << 3)];
    }
#pragma unroll
    for (int nt = 0; nt < 2; ++nt) {
      const int row = wn * 64 + nt * 16 + l15;
      const int base = row * 64, rx = row & 7;
      bf0[nt][0] = *(const bf16x8*)&Bb[base + ((quad ^ rx) << 3)];
      bf0[nt][1] = *(const bf16x8*)&Bb[base + (((quad + 4) ^ rx) << 3)];
    }
    stage2(t + 1, 1);
    asm volatile("s_waitcnt lgkmcnt(8)" ::: "memory");  // early-drain hint (12 reads)
    PBAR();
    WAIT_LGKM0();
    __builtin_amdgcn_s_setprio(1);
#pragma unroll
    for (int mt = 0; mt < 4; ++mt)
#pragma unroll
      for (int nt = 0; nt < 2; ++nt) {
        acc[mt][nt] = MM(af0[mt][0], bf0[nt][0], acc[mt][nt]);
        acc[mt][nt] = MM(af0[mt][1], bf0[nt][1], acc[mt][nt]);
      }
    __builtin_amdgcn_s_setprio(0);
    PBAR();

    // ---- phase 1: read bf1(4); stage (t+1, pair2); MFMA Q01 ----------------
#pragma unroll
    for (int nt = 0; nt < 2; ++nt) {
      const int row = wn * 64 + (nt + 2) * 16 + l15;
      const int base = row * 64, rx = row & 7;
      bf1[nt][0] = *(const bf16x8*)&Bb[base + ((quad ^ rx) << 3)];
      bf1[nt][1] = *(const bf16x8*)&Bb[base + (((quad + 4) ^ rx) << 3)];
    }
    stage2(t + 1, 2);
    PBAR();
    WAIT_LGKM0();
    __builtin_amdgcn_s_setprio(1);
#pragma unroll
    for (int mt = 0; mt < 4; ++mt)
#pragma unroll
      for (int nt = 0; nt < 2; ++nt) {
        acc[mt][nt + 2] = MM(af0[mt][0], bf1[nt][0], acc[mt][nt + 2]);
        acc[mt][nt + 2] = MM(af0[mt][1], bf1[nt][1], acc[mt][nt + 2]);
      }
    __builtin_amdgcn_s_setprio(0);
    PBAR();

    // ---- phase 2: read af1(8); stage (t+1, pair3); MFMA Q10 ----------------
#pragma unroll
    for (int mt = 0; mt < 4; ++mt) {
      const int row = wm * 128 + (mt + 4) * 16 + l15;
      const int base = row * 64, rx = row & 7;
      af1[mt][0] = *(const bf16x8*)&Ab[base + ((quad ^ rx) << 3)];
      af1[mt][1] = *(const bf16x8*)&Ab[base + (((quad + 4) ^ rx) << 3)];
    }
    stage2(t + 1, 3);
    PBAR();
    WAIT_LGKM0();
    __builtin_amdgcn_s_setprio(1);
#pragma unroll
    for (int mt = 0; mt < 4; ++mt)
#pragma unroll
      for (int nt = 0; nt < 2; ++nt) {
        acc[mt + 4][nt] = MM(af1[mt][0], bf0[nt][0], acc[mt + 4][nt]);
        acc[mt + 4][nt] = MM(af1[mt][1], bf0[nt][1], acc[mt + 4][nt]);
      }
    __builtin_amdgcn_s_setprio(0);
    PBAR();
    // B1: phase-2 gate drained all tile-t reads in every wave; buffer (t&1)
    // is free from here -> stage (t+2, pair0) in phase 3.

    // ---- phase 3: stage (t+2, pair0); MFMA Q11; counted boundary wait ------
    stage2(t + 2, 0);
    PBAR();
    WAIT_LGKM0();
    __builtin_amdgcn_s_setprio(1);
#pragma unroll
    for (int mt = 0; mt < 4; ++mt)
#pragma unroll
      for (int nt = 0; nt < 2; ++nt) {
        acc[mt + 4][nt + 2] = MM(af1[mt][0], bf1[nt][0], acc[mt + 4][nt + 2]);
        acc[mt + 4][nt + 2] = MM(af1[mt][1], bf1[nt][1], acc[mt + 4][nt + 2]);
      }
    __builtin_amdgcn_s_setprio(0);
    // boundary: all of tile t+1's loads must be retired; leave only the 2
    // loads of (t+2, pair0) outstanding.
    if (t + 2 < NT) {
      WAIT_VM(2);
    } else if (t + 1 < NT) {
      WAIT_VM(0);
    }
    PBAR();
  }

  // C/D layout: col = lane&15, row = quad*4 + reg; thread rows: mt(8) x r(4)
  const int nbase = n0 + wn * 64;

  if constexpr (EPI == 0) {  // QKV: +bias, fused d1 partial, coalesced bf16 store
    const int which = n0 >> 10;  // uniform per block
    const int nl0 = n0 & 1023;
    float bv4[4], dw[4];
#pragma unroll
    for (int nt = 0; nt < 4; ++nt) {
      const int col = wn * 64 + nt * 16 + l15;
      bv4[nt] = g.b_all[n0 + col];
      dw[nt] = (which == 0) ? b2f(g.de1[nl0 + col]) : 0.f;
    }
#pragma unroll
    for (int mt = 0; mt < 8; ++mt)
#pragma unroll
      for (int r = 0; r < 4; ++r) {
        const int row = wm * 128 + mt * 16 + quad * 4 + r;
        float part = 0.f;
#pragma unroll
        for (int nt = 0; nt < 4; ++nt) {
          const float v = acc[mt][nt][r] + bv4[nt];
          part += v * dw[nt];
          const int col = wn * 64 + nt * 16 + l15;
          const int chS = (col >> 3) ^ (row & 31);
          smem[row * 256 + chS * 8 + (col & 7)] = f2b(v);
        }
        if (which == 0) {
          part += __shfl_xor(part, 1);
          part += __shfl_xor(part, 2);
          part += __shfl_xor(part, 4);
          part += __shfl_xor(part, 8);
          if (l15 == 0) atomicAdd(&g.d1[m0 + row], part);
        }
      }
    __syncthreads();
    u16* dstbuf = which == 0 ? g.Qo : (which == 1 ? g.Ko : g.Vo);
#pragma unroll
    for (int p = 0; p < 16; ++p) {
      const int flat = p * 512 + tid;
      const int row = flat >> 5, chunk = flat & 31;
      const int chS = chunk ^ (row & 31);
      u16x8 v = *(const u16x8*)&smem[row * 256 + chS * 8];
      *(u16x8*)(dstbuf + (size_t)(m0 + row) * H_LEN + nl0 + chunk * 8) = v;
    }
  }

  if constexpr (EPI == 1) {  // scores: bitmask bias + exp, denom partial, P store
    float mk[4];
#pragma unroll
    for (int nt = 0; nt < 4; ++nt) mk[nt] = g.mask[bz * S_LEN + nbase + nt * 16 + l15];
    const size_t bSS = (size_t)bz * S_LEN * S_LEN;
    const int wbase = (n0 + wn * 64) >> 5;
#pragma unroll
    for (int mt = 0; mt < 8; ++mt)
#pragma unroll
      for (int r = 0; r < 4; ++r) {
        const int row = wm * 128 + mt * 16 + quad * 4 + r;
        const int gi = bz * S_LEN + m0 + row;
        const float d1v = g.d1[gi] * 0.03125f;
        const unsigned w0 = g.relbits[(size_t)gi * 64 + wbase];
        const unsigned w1 = g.relbits[(size_t)gi * 64 + wbase + 1];
        float dsum = 0.f;
#pragma unroll
        for (int nt = 0; nt < 4; ++nt) {
          const unsigned word = (nt & 2) ? w1 : w0;
          const int pos = (nt * 16 + l15) & 31;
          const float bias = ((word >> pos) & 1) ? d1v : 0.f;
          const float logit = acc[mt][nt][r] * 0.03125f + bias + mk[nt];
          const float pv = __expf(logit);  // logits bounded, no max-shift
          const u16 pb = f2b(pv);
          dsum += b2f(pb);  // denominator over the SAME bf16 values PV consumes
          const int col = wn * 64 + nt * 16 + l15;
          const int chS = (col >> 3) ^ (row & 31);
          smem[row * 256 + chS * 8 + (col & 7)] = pb;
        }
        dsum += __shfl_xor(dsum, 1);
        dsum += __shfl_xor(dsum, 2);
        dsum += __shfl_xor(dsum, 4);
        dsum += __shfl_xor(dsum, 8);
        if (l15 == 0) atomicAdd(&g.denom[gi], dsum);
      }
    __syncthreads();
#pragma unroll
    for (int p = 0; p < 16; ++p) {
      const int flat = p * 512 + tid;
      const int row = flat >> 5, chunk = flat & 31;
      const int chS = chunk ^ (row & 31);
      u16x8 v = *(const u16x8*)&smem[row * 256 + chS * 8];
      *(u16x8*)(g.P + bSS + (size_t)(m0 + row) * S_LEN + n0 + chunk * 8) = v;
    }
  }

  if constexpr (EPI == 2) {  // ctx: normalize by EPI1's denom, fp32 store
    const size_t ob = (size_t)bz * S_LEN * H_LEN;
#pragma unroll
    for (int mt = 0; mt < 8; ++mt)
#pragma unroll
      for (int r = 0; r < 4; ++r) {
        const int row = wm * 128 + mt * 16 + quad * 4 + r;
        const float inv = 1.0f / g.denom[bz * S_LEN + m0 + row];
        const size_t rowo = ob + (size_t)(m0 + row) * H_LEN;
#pragma unroll
        for (int nt = 0; nt < 4; ++nt)
          g.outp[rowo + nbase + nt * 16 + l15] = acc[mt][nt][r] * inv;
      }
  }
}

// ---------------- V[b][j][d] -> Vt[b][d][j] -----------------------------------
__global__ __launch_bounds__(256) void transpose_v(const u16* __restrict__ V,
                                                   u16* __restrict__ Vt) {
  const int b = blockIdx.z;
  const int j0 = blockIdx.x * 64;
  const int d0 = blockIdx.y * 64;
  __shared__ u16 t[64][72];
  const int tid = threadIdx.x;
  const int tr = tid >> 4;
  const int tc = (tid & 15) * 4;
#pragma unroll
  for (int p = 0; p < 4; ++p) {
    const int jl = p * 16 + tr;
    const u16* src = V + ((size_t)b * S_LEN + (j0 + jl)) * H_LEN + d0 + tc;
    ushort4 v = *(const ushort4*)src;
    t[jl][tc + 0] = v.x; t[jl][tc + 1] = v.y; t[jl][tc + 2] = v.z; t[jl][tc + 3] = v.w;
  }
  __syncthreads();
#pragma unroll
  for (int p = 0; p < 4; ++p) {
    const int dl = p * 16 + tr;
    ushort4 v;
    v.x = t[tc + 0][dl]; v.y = t[tc + 1][dl]; v.z = t[tc + 2][dl]; v.w = t[tc + 3][dl];
    *(ushort4*)(Vt + ((size_t)b * H_LEN + (d0 + dl)) * S_LEN + j0 + tc) = v;
  }
}

extern "C" void kernel_launch(void* const* d_in, const int* in_sizes, int n_in,
                              void* d_out, int out_size, void* d_ws, size_t ws_size,
                              hipStream_t stream) {
  (void)in_sizes; (void)n_in; (void)out_size; (void)ws_size;
  const float* X    = (const float*)d_in[0];
  const float* mask = (const float*)d_in[1];
  const int*   rel  = (const int*)d_in[2];
  const float* Wq   = (const float*)d_in[3];
  const float* bq   = (const float*)d_in[4];
  const float* Wk   = (const float*)d_in[5];
  const float* bk   = (const float*)d_in[6];
  const float* Wv   = (const float*)d_in[7];
  const float* bv   = (const float*)d_in[8];
  const float* dist = (const float*)d_in[9];
  float* out = (float*)d_out;

  char* p = (char*)d_ws;
  u16* Xbf = (u16*)p;      p += (size_t)16384 * 1024 * 2;
  u16* Wbf = (u16*)p;      p += (size_t)3072 * 1024 * 2;
  float* b_all = (float*)p; p += 3072 * 4;
  u16* de1 = (u16*)p;      p += 4096;
  u16* Qb = (u16*)p;       p += (size_t)16384 * 1024 * 2;
  u16* Kb = (u16*)p;       p += (size_t)16384 * 1024 * 2;
  u16* Vb = (u16*)p;       p += (size_t)16384 * 1024 * 2;
  u16* Vt = (u16*)p;       p += (size_t)16384 * 1024 * 2;
  float* d1 = (float*)p;   p += 16384 * 4;
  float* denom = (float*)p; p += 16384 * 4;   // zeroed together with d1 in prep
  unsigned* relbits = (unsigned*)p; p += (size_t)1048576 * 4;
  u16* P = (u16*)p;        p += (size_t)8 * 2048 * 2048 * 2;

  prep_kernel<<<1024, 256, 0, stream>>>(X, Wq, Wk, Wv, bq, bk, bv, dist, rel,
                                        Xbf, Wbf, b_all, de1, relbits, d1);

  GArgs g0 = {};
  g0.A = Xbf; g0.B = Wbf; g0.sA = 0; g0.sB = 0;
  g0.ldA = 1024; g0.ldB = 1024; g0.K = 1024;
  g0.Qo = Qb; g0.Ko = Kb; g0.Vo = Vb; g0.b_all = b_all; g0.de1 = de1; g0.d1 = d1;
  gemm256<0><<<dim3(768, 1, 1), dim3(512, 1, 1), 0, stream>>>(g0);

  transpose_v<<<dim3(32, 16, 8), dim3(256, 1, 1), 0, stream>>>(Vb, Vt);

  GArgs g1 = {};
  g1.A = Qb; g1.B = Kb; g1.sA = 2048LL * 1024; g1.sB = 2048LL * 1024;
  g1.ldA = 1024; g1.ldB = 1024; g1.K = 1024;
  g1.relbits = relbits; g1.d1 = d1; g1.mask = mask; g1.P = P; g1.denom = denom;
  gemm256<1><<<dim3(512, 1, 1), dim3(512, 1, 1), 0, stream>>>(g1);

  GArgs g2 = {};
  g2.A = P; g2.B = Vt; g2.sA = 2048LL * 2048; g2.sB = 1024LL * 2048;
  g2.ldA = 2048; g2.ldB = 2048; g2.K = 2048;
  g2.denom = denom; g2.outp = out;
  gemm256<2><<<dim3(256, 1, 1), dim3(512, 1, 1), 0, stream>>>(g2);
}

// Round 5
// 570.001 us; speedup vs baseline: 1.0421x; 1.0421x over previous
//
#include <hip/hip_runtime.h>

typedef unsigned short u16;
typedef __bf16 bf16x8 __attribute__((ext_vector_type(8)));
typedef u16 u16x8 __attribute__((ext_vector_type(8)));
typedef float f32x4 __attribute__((ext_vector_type(4)));

#define S_LEN 2048
#define H_LEN 1024

__device__ __forceinline__ u16 f2b(float f) {
  unsigned u = __float_as_uint(f);
  return (u16)((u + 0x7FFFu + ((u >> 16) & 1u)) >> 16);  // RNE
}
__device__ __forceinline__ float b2f(u16 h) { return __uint_as_float(((unsigned)h) << 16); }

#define GLOAD16(gp, lp)                                   \
  __builtin_amdgcn_global_load_lds(                       \
      (__attribute__((address_space(1))) void*)(gp),      \
      (__attribute__((address_space(3))) void*)(lp), 16, 0, 0)

#define FENCE() asm volatile("" ::: "memory")
#define PBAR()                           \
  do {                                   \
    FENCE();                             \
    __builtin_amdgcn_s_barrier();        \
    FENCE();                             \
  } while (0)
#define WAIT_LGKM0()                                        \
  do {                                                      \
    asm volatile("s_waitcnt lgkmcnt(0)" ::: "memory");      \
    __builtin_amdgcn_sched_barrier(0);                      \
  } while (0)
#define WAIT_VM(n) asm volatile("s_waitcnt vmcnt(" #n ")" ::: "memory")

__device__ __forceinline__ f32x4 MM(bf16x8 a, bf16x8 b, f32x4 c) {
  return __builtin_amdgcn_mfma_f32_16x16x32_bf16(a, b, c, 0, 0, 0);
}

// ---------------- prep: casts, bias pack, relbits pack (ballot), zero d1+denom
__global__ __launch_bounds__(256) void prep_kernel(
    const float* __restrict__ X, const float* __restrict__ Wq,
    const float* __restrict__ Wk, const float* __restrict__ Wv,
    const float* __restrict__ bq, const float* __restrict__ bk,
    const float* __restrict__ bv, const float* __restrict__ dist,
    const int* __restrict__ rel,
    u16* __restrict__ Xbf, u16* __restrict__ Wbf, float* __restrict__ b_all,
    u16* __restrict__ de1, unsigned* __restrict__ bits, float* __restrict__ d1) {
  size_t tid = (size_t)blockIdx.x * blockDim.x + threadIdx.x;
  size_t nth = (size_t)gridDim.x * blockDim.x;
  const int lane = threadIdx.x & 63;
  for (size_t i = tid; i < 4194304u; i += nth) {  // X: 16.7M floats / 4
    float4 v = ((const float4*)X)[i];
    ushort4 o; o.x = f2b(v.x); o.y = f2b(v.y); o.z = f2b(v.z); o.w = f2b(v.w);
    ((ushort4*)Xbf)[i] = o;
  }
  for (size_t i = tid; i < 786432u; i += nth) {  // Wq|Wk|Wv
    int which = (int)(i >> 18);
    size_t off = i & 262143u;
    const float4* src = (const float4*)(which == 0 ? Wq : (which == 1 ? Wk : Wv));
    float4 v = src[off];
    ushort4 o; o.x = f2b(v.x); o.y = f2b(v.y); o.z = f2b(v.z); o.w = f2b(v.w);
    ((ushort4*)Wbf)[i] = o;
  }
  // relbits: coalesced — lane c reads int4, nibble-packs, 3x shfl_xor assembles
  // the 32-bit word from 8 consecutive lanes. 8.4M int4 total.
  const int4* r4 = (const int4*)rel;
  for (size_t c = tid; c < 8388608u; c += nth) {
    int4 v = r4[c];
    unsigned nib = (unsigned)(v.x == 1) | ((unsigned)(v.y == 1) << 1) |
                   ((unsigned)(v.z == 1) << 2) | ((unsigned)(v.w == 1) << 3);
    unsigned o1 = __shfl_xor((int)nib, 1);
    nib = (lane & 1) ? (o1 | (nib << 4)) : (nib | (o1 << 4));
    unsigned o2 = __shfl_xor((int)nib, 2);
    nib = (lane & 2) ? (o2 | (nib << 8)) : (nib | (o2 << 8));
    unsigned o4 = __shfl_xor((int)nib, 4);
    nib = (lane & 4) ? (o4 | (nib << 16)) : (nib | (o4 << 16));
    if ((lane & 7) == 0) bits[c >> 3] = nib;
  }
  for (size_t i = tid; i < 256u; i += nth) {  // dist_emb row 1
    float4 v = ((const float4*)(dist + H_LEN))[i];
    ushort4 o; o.x = f2b(v.x); o.y = f2b(v.y); o.z = f2b(v.z); o.w = f2b(v.w);
    ((ushort4*)de1)[i] = o;
  }
  for (size_t i = tid; i < 3072u; i += nth)
    b_all[i] = (i < 1024) ? bq[i] : (i < 2048 ? bk[i - 1024] : bv[i - 2048]);
  for (size_t i = tid; i < 32768u; i += nth) d1[i] = 0.f;  // d1 + denom
}

// ---------------- 256x256 NT-GEMM, BK=64 ------------------------------------
struct GArgs {
  const u16* A; const u16* B;
  long long sA, sB;
  int ldA, ldB, K;
  u16 *Qo, *Ko, *Vt; const float* b_all; const u16* de1; float* d1;       // EPI 0
  const unsigned* relbits; const float* mask; u16* P; float* denom;       // EPI 1
  float* outp;                                                            // EPI 2
};

template <int EPI>
__global__ __launch_bounds__(512, 2) void gemm256(GArgs g) {
  int bx, by, bz;
  {
    const int lin = blockIdx.x;
    if constexpr (EPI == 0) {        // 768 blocks: 96/XCD band swizzle (R1-good)
      const int wg = (lin & 7) * 96 + (lin >> 3);
      by = wg / 12; bx = wg % 12; bz = 0;
    } else if constexpr (EPI == 1) { // 512 blocks: NATURAL grid (R1-good)
      bx = lin & 7; by = (lin >> 3) & 7; bz = lin >> 6;
    } else {                         // 256 blocks: batch-per-XCD (R2-good, keep)
      const int wg = (lin & 7) * 32 + (lin >> 3);
      bz = wg >> 5; by = (wg >> 2) & 7; bx = wg & 3;
    }
  }
  const u16* Abase = g.A + (size_t)bz * g.sA;
  const u16* Bbase = g.B + (size_t)bz * g.sB;
  const int m0 = by * 256, n0 = bx * 256;

  __shared__ u16 smem[65536];  // 128 KiB: [buf0: A 32K|B 32K][buf1: A 32K|B 32K]

  const int tid = threadIdx.x;
  const int lane = tid & 63, w = tid >> 6;
  const int wm = w >> 2, wn = w & 3;          // 2 x 4 waves, wave tile 128 x 64
  const int l15 = lane & 15, quad = lane >> 4;

  f32x4 acc[8][4];
  const f32x4 zero = {0.f, 0.f, 0.f, 0.f};
#pragma unroll
  for (int a = 0; a < 8; ++a)
#pragma unroll
    for (int b = 0; b < 4; ++b) acc[a][b] = zero;

  // staging: LDS written linearly; global SOURCE pre-swizzled with the same XOR
  // used on ds_read (both-sides-or-neither rule)
  const u16* gA[4]; const u16* gB[4]; int qoff[4];
#pragma unroll
  for (int r = 0; r < 4; ++r) {
    const int q = r * 512 + tid;        // 16B-chunk id in [0,2048)
    const int row = q >> 3, ch = q & 7;
    const int chS = ch ^ (row & 7);
    gA[r] = Abase + (size_t)(m0 + row) * g.ldA + chS * 8;
    gB[r] = Bbase + (size_t)(n0 + row) * g.ldB + chS * 8;
    qoff[r] = q * 8;                    // u16 offset in tile
  }

  const int NT = g.K >> 6;

  auto stageFull = [&](int boff2, int kt) {
#pragma unroll
    for (int r = 0; r < 4; ++r) GLOAD16(gA[r] + kt, &smem[boff2 + qoff[r]]);
#pragma unroll
    for (int r = 0; r < 4; ++r) GLOAD16(gB[r] + kt, &smem[boff2 + 16384 + qoff[r]]);
  };
  auto stage2 = [&](int tile, int pr) {   // fine variant (EPI2 only)
    if (tile >= NT) return;
    const int boff2 = (tile & 1) << 15;
    const int kt = tile << 6;
    if (pr < 2) {
      GLOAD16(gA[2 * pr] + kt,     &smem[boff2 + qoff[2 * pr]]);
      GLOAD16(gA[2 * pr + 1] + kt, &smem[boff2 + qoff[2 * pr + 1]]);
    } else {
      const int r = 2 * (pr - 2);
      GLOAD16(gB[r] + kt,     &smem[boff2 + 16384 + qoff[r]]);
      GLOAD16(gB[r + 1] + kt, &smem[boff2 + 16384 + qoff[r + 1]]);
    }
  };

  bf16x8 af0[4][2], af1[4][2], bf0[2][2], bf1[2][2];

  if constexpr (EPI != 2) {
    // ======== R1 coarse 4-phase loop (measured best: 141.9 µs EPI0) ========
    stageFull(0, 0);
    if (1 < NT) stageFull(32768, 64);
    WAIT_VM(8);
    PBAR();

    for (int t = 0; t < NT; ++t) {
      const int boff = (t & 1) << 15;
      const u16* Ab = smem + boff;
      const u16* Bb = smem + boff + 16384;

      // phase 0: read af0(8) + bf0(4); MFMA Q00
#pragma unroll
      for (int mt = 0; mt < 4; ++mt) {
        const int row = wm * 128 + mt * 16 + l15;
        const int base = row * 64, rx = row & 7;
        af0[mt][0] = *(const bf16x8*)&Ab[base + ((quad ^ rx) << 3)];
        af0[mt][1] = *(const bf16x8*)&Ab[base + (((quad + 4) ^ rx) << 3)];
      }
#pragma unroll
      for (int nt = 0; nt < 2; ++nt) {
        const int row = wn * 64 + nt * 16 + l15;
        const int base = row * 64, rx = row & 7;
        bf0[nt][0] = *(const bf16x8*)&Bb[base + ((quad ^ rx) << 3)];
        bf0[nt][1] = *(const bf16x8*)&Bb[base + (((quad + 4) ^ rx) << 3)];
      }
      asm volatile("s_waitcnt lgkmcnt(8)" ::: "memory");
      PBAR();
      WAIT_LGKM0();
      __builtin_amdgcn_s_setprio(1);
#pragma unroll
      for (int mt = 0; mt < 4; ++mt)
#pragma unroll
        for (int nt = 0; nt < 2; ++nt) {
          acc[mt][nt] = MM(af0[mt][0], bf0[nt][0], acc[mt][nt]);
          acc[mt][nt] = MM(af0[mt][1], bf0[nt][1], acc[mt][nt]);
        }
      __builtin_amdgcn_s_setprio(0);
      PBAR();

      // phase 1: read bf1(4); MFMA Q01
#pragma unroll
      for (int nt = 0; nt < 2; ++nt) {
        const int row = wn * 64 + (nt + 2) * 16 + l15;
        const int base = row * 64, rx = row & 7;
        bf1[nt][0] = *(const bf16x8*)&Bb[base + ((quad ^ rx) << 3)];
        bf1[nt][1] = *(const bf16x8*)&Bb[base + (((quad + 4) ^ rx) << 3)];
      }
      PBAR();
      WAIT_LGKM0();
      __builtin_amdgcn_s_setprio(1);
#pragma unroll
      for (int mt = 0; mt < 4; ++mt)
#pragma unroll
        for (int nt = 0; nt < 2; ++nt) {
          acc[mt][nt + 2] = MM(af0[mt][0], bf1[nt][0], acc[mt][nt + 2]);
          acc[mt][nt + 2] = MM(af0[mt][1], bf1[nt][1], acc[mt][nt + 2]);
        }
      __builtin_amdgcn_s_setprio(0);
      PBAR();

      // phase 2: read af1(8); MFMA Q10
#pragma unroll
      for (int mt = 0; mt < 4; ++mt) {
        const int row = wm * 128 + (mt + 4) * 16 + l15;
        const int base = row * 64, rx = row & 7;
        af1[mt][0] = *(const bf16x8*)&Ab[base + ((quad ^ rx) << 3)];
        af1[mt][1] = *(const bf16x8*)&Ab[base + (((quad + 4) ^ rx) << 3)];
      }
      PBAR();
      WAIT_LGKM0();
      __builtin_amdgcn_s_setprio(1);
#pragma unroll
      for (int mt = 0; mt < 4; ++mt)
#pragma unroll
        for (int nt = 0; nt < 2; ++nt) {
          acc[mt + 4][nt] = MM(af1[mt][0], bf0[nt][0], acc[mt + 4][nt]);
          acc[mt + 4][nt] = MM(af1[mt][1], bf0[nt][1], acc[mt + 4][nt]);
        }
      __builtin_amdgcn_s_setprio(0);
      PBAR();

      // phase 3: stage(t+2) burst into freed buffer; MFMA Q11; vmcnt(8)
      if (t + 2 < NT) stageFull(boff, (t + 2) << 6);
      PBAR();
      WAIT_LGKM0();
      __builtin_amdgcn_s_setprio(1);
#pragma unroll
      for (int mt = 0; mt < 4; ++mt)
#pragma unroll
        for (int nt = 0; nt < 2; ++nt) {
          acc[mt + 4][nt + 2] = MM(af1[mt][0], bf1[nt][0], acc[mt + 4][nt + 2]);
          acc[mt + 4][nt + 2] = MM(af1[mt][1], bf1[nt][1], acc[mt + 4][nt + 2]);
        }
      __builtin_amdgcn_s_setprio(0);
      if (t + 2 < NT) {
        WAIT_VM(8);
      } else if (t + 1 < NT) {
        WAIT_VM(0);
      }
      PBAR();
    }
  } else {
    // ======== R4 fine-staged loop (EPI2: ~88 µs, keep frozen) ==============
    stage2(0, 0); stage2(0, 1); stage2(0, 2); stage2(0, 3);
    stage2(1, 0);
    if (1 < NT) { WAIT_VM(2); } else { WAIT_VM(0); }
    PBAR();

    for (int t = 0; t < NT; ++t) {
      const int boff = (t & 1) << 15;
      const u16* Ab = smem + boff;
      const u16* Bb = smem + boff + 16384;

#pragma unroll
      for (int mt = 0; mt < 4; ++mt) {
        const int row = wm * 128 + mt * 16 + l15;
        const int base = row * 64, rx = row & 7;
        af0[mt][0] = *(const bf16x8*)&Ab[base + ((quad ^ rx) << 3)];
        af0[mt][1] = *(const bf16x8*)&Ab[base + (((quad + 4) ^ rx) << 3)];
      }
#pragma unroll
      for (int nt = 0; nt < 2; ++nt) {
        const int row = wn * 64 + nt * 16 + l15;
        const int base = row * 64, rx = row & 7;
        bf0[nt][0] = *(const bf16x8*)&Bb[base + ((quad ^ rx) << 3)];
        bf0[nt][1] = *(const bf16x8*)&Bb[base + (((quad + 4) ^ rx) << 3)];
      }
      stage2(t + 1, 1);
      asm volatile("s_waitcnt lgkmcnt(8)" ::: "memory");
      PBAR();
      WAIT_LGKM0();
      __builtin_amdgcn_s_setprio(1);
#pragma unroll
      for (int mt = 0; mt < 4; ++mt)
#pragma unroll
        for (int nt = 0; nt < 2; ++nt) {
          acc[mt][nt] = MM(af0[mt][0], bf0[nt][0], acc[mt][nt]);
          acc[mt][nt] = MM(af0[mt][1], bf0[nt][1], acc[mt][nt]);
        }
      __builtin_amdgcn_s_setprio(0);
      PBAR();

#pragma unroll
      for (int nt = 0; nt < 2; ++nt) {
        const int row = wn * 64 + (nt + 2) * 16 + l15;
        const int base = row * 64, rx = row & 7;
        bf1[nt][0] = *(const bf16x8*)&Bb[base + ((quad ^ rx) << 3)];
        bf1[nt][1] = *(const bf16x8*)&Bb[base + (((quad + 4) ^ rx) << 3)];
      }
      stage2(t + 1, 2);
      PBAR();
      WAIT_LGKM0();
      __builtin_amdgcn_s_setprio(1);
#pragma unroll
      for (int mt = 0; mt < 4; ++mt)
#pragma unroll
        for (int nt = 0; nt < 2; ++nt) {
          acc[mt][nt + 2] = MM(af0[mt][0], bf1[nt][0], acc[mt][nt + 2]);
          acc[mt][nt + 2] = MM(af0[mt][1], bf1[nt][1], acc[mt][nt + 2]);
        }
      __builtin_amdgcn_s_setprio(0);
      PBAR();

#pragma unroll
      for (int mt = 0; mt < 4; ++mt) {
        const int row = wm * 128 + (mt + 4) * 16 + l15;
        const int base = row * 64, rx = row & 7;
        af1[mt][0] = *(const bf16x8*)&Ab[base + ((quad ^ rx) << 3)];
        af1[mt][1] = *(const bf16x8*)&Ab[base + (((quad + 4) ^ rx) << 3)];
      }
      stage2(t + 1, 3);
      PBAR();
      WAIT_LGKM0();
      __builtin_amdgcn_s_setprio(1);
#pragma unroll
      for (int mt = 0; mt < 4; ++mt)
#pragma unroll
        for (int nt = 0; nt < 2; ++nt) {
          acc[mt + 4][nt] = MM(af1[mt][0], bf0[nt][0], acc[mt + 4][nt]);
          acc[mt + 4][nt] = MM(af1[mt][1], bf0[nt][1], acc[mt + 4][nt]);
        }
      __builtin_amdgcn_s_setprio(0);
      PBAR();

      stage2(t + 2, 0);
      PBAR();
      WAIT_LGKM0();
      __builtin_amdgcn_s_setprio(1);
#pragma unroll
      for (int mt = 0; mt < 4; ++mt)
#pragma unroll
        for (int nt = 0; nt < 2; ++nt) {
          acc[mt + 4][nt + 2] = MM(af1[mt][0], bf1[nt][0], acc[mt + 4][nt + 2]);
          acc[mt + 4][nt + 2] = MM(af1[mt][1], bf1[nt][1], acc[mt + 4][nt + 2]);
        }
      __builtin_amdgcn_s_setprio(0);
      if (t + 2 < NT) {
        WAIT_VM(2);
      } else if (t + 1 < NT) {
        WAIT_VM(0);
      }
      PBAR();
    }
  }

  // C/D layout: col = lane&15, row = quad*4 + reg; thread rows: mt(8) x r(4)
  const int nbase = n0 + wn * 64;

  if constexpr (EPI == 0) {
    const int which = n0 >> 10;  // 0=Q, 1=K, 2=V — uniform per block
    const int nl0 = n0 & 1023;
    float bv4[4], dw[4];
#pragma unroll
    for (int nt = 0; nt < 4; ++nt) {
      const int col = wn * 64 + nt * 16 + l15;
      bv4[nt] = g.b_all[n0 + col];
      dw[nt] = (which == 0) ? b2f(g.de1[nl0 + col]) : 0.f;
    }
    if (which < 2) {  // Q / K: row-major bf16 store + fused d1 partial (Q)
#pragma unroll
      for (int mt = 0; mt < 8; ++mt)
#pragma unroll
        for (int r = 0; r < 4; ++r) {
          const int row = wm * 128 + mt * 16 + quad * 4 + r;
          float part = 0.f;
#pragma unroll
          for (int nt = 0; nt < 4; ++nt) {
            const float v = acc[mt][nt][r] + bv4[nt];
            part += v * dw[nt];
            const int col = wn * 64 + nt * 16 + l15;
            const int chS = (col >> 3) ^ (row & 31);
            smem[row * 256 + chS * 8 + (col & 7)] = f2b(v);
          }
          if (which == 0) {
            part += __shfl_xor(part, 1);
            part += __shfl_xor(part, 2);
            part += __shfl_xor(part, 4);
            part += __shfl_xor(part, 8);
            if (l15 == 0) atomicAdd(&g.d1[m0 + row], part);
          }
        }
      __syncthreads();
      u16* dstbuf = which == 0 ? g.Qo : g.Ko;
#pragma unroll
      for (int p = 0; p < 16; ++p) {
        const int flat = p * 512 + tid;
        const int row = flat >> 5, chunk = flat & 31;
        const int chS = chunk ^ (row & 31);
        u16x8 v = *(const u16x8*)&smem[row * 256 + chS * 8];
        *(u16x8*)(dstbuf + (size_t)(m0 + row) * H_LEN + nl0 + chunk * 8) = v;
      }
    } else {  // V: store tile TRANSPOSED in smem, write Vt[b][dim][seq] direct
#pragma unroll
      for (int mt = 0; mt < 8; ++mt)
#pragma unroll
        for (int r = 0; r < 4; ++r) {
          const int row = wm * 128 + mt * 16 + quad * 4 + r;  // seq-local
#pragma unroll
          for (int nt = 0; nt < 4; ++nt) {
            const float v = acc[mt][nt][r] + bv4[nt];
            const int col = wn * 64 + nt * 16 + l15;          // dim-local
            const int chS = (row >> 3) ^ (col & 31);
            smem[col * 256 + chS * 8 + (row & 7)] = f2b(v);
          }
        }
      __syncthreads();
      const int batch = m0 >> 11, sl0 = m0 & 2047;
#pragma unroll
      for (int p = 0; p < 16; ++p) {
        const int flat = p * 512 + tid;
        const int dimc = flat >> 5, chunk = flat & 31;        // chunk over seq
        const int chS = chunk ^ (dimc & 31);
        u16x8 v = *(const u16x8*)&smem[dimc * 256 + chS * 8];
        *(u16x8*)(g.Vt + ((size_t)batch * H_LEN + nl0 + dimc) * S_LEN + sl0 +
                  chunk * 8) = v;
      }
    }
  }

  if constexpr (EPI == 1) {  // scores: bitmask bias + exp, denom partial, P store
    float mk[4];
#pragma unroll
    for (int nt = 0; nt < 4; ++nt) mk[nt] = g.mask[bz * S_LEN + nbase + nt * 16 + l15];
    const size_t bSS = (size_t)bz * S_LEN * S_LEN;
    const int wbase = (n0 + wn * 64) >> 5;
#pragma unroll
    for (int mt = 0; mt < 8; ++mt)
#pragma unroll
      for (int r = 0; r < 4; ++r) {
        const int row = wm * 128 + mt * 16 + quad * 4 + r;
        const int gi = bz * S_LEN + m0 + row;
        const float d1v = g.d1[gi] * 0.03125f;
        const unsigned w0 = g.relbits[(size_t)gi * 64 + wbase];
        const unsigned w1 = g.relbits[(size_t)gi * 64 + wbase + 1];
        float dsum = 0.f;
#pragma unroll
        for (int nt = 0; nt < 4; ++nt) {
          const unsigned word = (nt & 2) ? w1 : w0;
          const int pos = (nt * 16 + l15) & 31;
          const float bias = ((word >> pos) & 1) ? d1v : 0.f;
          const float logit = acc[mt][nt][r] * 0.03125f + bias + mk[nt];
          const float pv = __expf(logit);  // logits bounded, no max-shift
          const u16 pb = f2b(pv);
          dsum += b2f(pb);  // denominator over the SAME bf16 values PV consumes
          const int col = wn * 64 + nt * 16 + l15;
          const int chS = (col >> 3) ^ (row & 31);
          smem[row * 256 + chS * 8 + (col & 7)] = pb;
        }
        dsum += __shfl_xor(dsum, 1);
        dsum += __shfl_xor(dsum, 2);
        dsum += __shfl_xor(dsum, 4);
        dsum += __shfl_xor(dsum, 8);
        if (l15 == 0) atomicAdd(&g.denom[gi], dsum);
      }
    __syncthreads();
#pragma unroll
    for (int p = 0; p < 16; ++p) {
      const int flat = p * 512 + tid;
      const int row = flat >> 5, chunk = flat & 31;
      const int chS = chunk ^ (row & 31);
      u16x8 v = *(const u16x8*)&smem[row * 256 + chS * 8];
      *(u16x8*)(g.P + bSS + (size_t)(m0 + row) * S_LEN + n0 + chunk * 8) = v;
    }
  }

  if constexpr (EPI == 2) {  // ctx: normalize by EPI1's denom, fp32 store
    const size_t ob = (size_t)bz * S_LEN * H_LEN;
#pragma unroll
    for (int mt = 0; mt < 8; ++mt)
#pragma unroll
      for (int r = 0; r < 4; ++r) {
        const int row = wm * 128 + mt * 16 + quad * 4 + r;
        const float inv = 1.0f / g.denom[bz * S_LEN + m0 + row];
        const size_t rowo = ob + (size_t)(m0 + row) * H_LEN;
#pragma unroll
        for (int nt = 0; nt < 4; ++nt)
          g.outp[rowo + nbase + nt * 16 + l15] = acc[mt][nt][r] * inv;
      }
  }
}

extern "C" void kernel_launch(void* const* d_in, const int* in_sizes, int n_in,
                              void* d_out, int out_size, void* d_ws, size_t ws_size,
                              hipStream_t stream) {
  (void)in_sizes; (void)n_in; (void)out_size; (void)ws_size;
  const float* X    = (const float*)d_in[0];
  const float* mask = (const float*)d_in[1];
  const int*   rel  = (const int*)d_in[2];
  const float* Wq   = (const float*)d_in[3];
  const float* bq   = (const float*)d_in[4];
  const float* Wk   = (const float*)d_in[5];
  const float* bk   = (const float*)d_in[6];
  const float* Wv   = (const float*)d_in[7];
  const float* bv   = (const float*)d_in[8];
  const float* dist = (const float*)d_in[9];
  float* out = (float*)d_out;

  char* p = (char*)d_ws;
  u16* Xbf = (u16*)p;      p += (size_t)16384 * 1024 * 2;
  u16* Wbf = (u16*)p;      p += (size_t)3072 * 1024 * 2;
  float* b_all = (float*)p; p += 3072 * 4;
  u16* de1 = (u16*)p;      p += 4096;
  u16* Qb = (u16*)p;       p += (size_t)16384 * 1024 * 2;
  u16* Kb = (u16*)p;       p += (size_t)16384 * 1024 * 2;
  u16* Vt = (u16*)p;       p += (size_t)16384 * 1024 * 2;
  float* d1 = (float*)p;   p += 16384 * 4;
  float* denom = (float*)p; p += 16384 * 4;   // zeroed together with d1 in prep
  unsigned* relbits = (unsigned*)p; p += (size_t)1048576 * 4;
  u16* P = (u16*)p;        p += (size_t)8 * 2048 * 2048 * 2;

  prep_kernel<<<1024, 256, 0, stream>>>(X, Wq, Wk, Wv, bq, bk, bv, dist, rel,
                                        Xbf, Wbf, b_all, de1, relbits, d1);

  GArgs g0 = {};
  g0.A = Xbf; g0.B = Wbf; g0.sA = 0; g0.sB = 0;
  g0.ldA = 1024; g0.ldB = 1024; g0.K = 1024;
  g0.Qo = Qb; g0.Ko = Kb; g0.Vt = Vt; g0.b_all = b_all; g0.de1 = de1; g0.d1 = d1;
  gemm256<0><<<dim3(768, 1, 1), dim3(512, 1, 1), 0, stream>>>(g0);

  GArgs g1 = {};
  g1.A = Qb; g1.B = Kb; g1.sA = 2048LL * 1024; g1.sB = 2048LL * 1024;
  g1.ldA = 1024; g1.ldB = 1024; g1.K = 1024;
  g1.relbits = relbits; g1.d1 = d1; g1.mask = mask; g1.P = P; g1.denom = denom;
  gemm256<1><<<dim3(512, 1, 1), dim3(512, 1, 1), 0, stream>>>(g1);

  GArgs g2 = {};
  g2.A = P; g2.B = Vt; g2.sA = 2048LL * 2048; g2.sB = 1024LL * 2048;
  g2.ldA = 2048; g2.ldB = 2048; g2.K = 2048;
  g2.denom = denom; g2.outp = out;
  gemm256<2><<<dim3(256, 1, 1), dim3(512, 1, 1), 0, stream>>>(g2);
}

// Round 7
// 566.847 us; speedup vs baseline: 1.0479x; 1.0056x over previous
//
#include <hip/hip_runtime.h>

typedef unsigned short u16;
typedef __bf16 bf16x8 __attribute__((ext_vector_type(8)));
typedef u16 u16x8 __attribute__((ext_vector_type(8)));
typedef float f32x4 __attribute__((ext_vector_type(4)));

#define S_LEN 2048
#define H_LEN 1024

__device__ __forceinline__ u16 f2b(float f) {
  unsigned u = __float_as_uint(f);
  return (u16)((u + 0x7FFFu + ((u >> 16) & 1u)) >> 16);  // RNE
}
__device__ __forceinline__ float b2f(u16 h) { return __uint_as_float(((unsigned)h) << 16); }

#define GLOAD16(gp, lp)                                   \
  __builtin_amdgcn_global_load_lds(                       \
      (__attribute__((address_space(1))) void*)(gp),      \
      (__attribute__((address_space(3))) void*)(lp), 16, 0, 0)

#define FENCE() asm volatile("" ::: "memory")
#define PBAR()                           \
  do {                                   \
    FENCE();                             \
    __builtin_amdgcn_s_barrier();        \
    FENCE();                             \
  } while (0)
#define WAIT_LGKM0()                                        \
  do {                                                      \
    asm volatile("s_waitcnt lgkmcnt(0)" ::: "memory");      \
    __builtin_amdgcn_sched_barrier(0);                      \
  } while (0)
#define WAIT_VM(n) asm volatile("s_waitcnt vmcnt(" #n ")" ::: "memory")

__device__ __forceinline__ f32x4 MM(bf16x8 a, bf16x8 b, f32x4 c) {
  return __builtin_amdgcn_mfma_f32_16x16x32_bf16(a, b, c, 0, 0, 0);
}

// ---------------- prep: casts, bias pack, relbits pack (ballot), zero d1+denom
__global__ __launch_bounds__(256) void prep_kernel(
    const float* __restrict__ X, const float* __restrict__ Wq,
    const float* __restrict__ Wk, const float* __restrict__ Wv,
    const float* __restrict__ bq, const float* __restrict__ bk,
    const float* __restrict__ bv, const float* __restrict__ dist,
    const int* __restrict__ rel,
    u16* __restrict__ Xbf, u16* __restrict__ Wbf, float* __restrict__ b_all,
    u16* __restrict__ de1, unsigned* __restrict__ bits, float* __restrict__ d1) {
  size_t tid = (size_t)blockIdx.x * blockDim.x + threadIdx.x;
  size_t nth = (size_t)gridDim.x * blockDim.x;
  const int lane = threadIdx.x & 63;
  for (size_t i = tid; i < 4194304u; i += nth) {  // X: 16.7M floats / 4
    float4 v = ((const float4*)X)[i];
    ushort4 o; o.x = f2b(v.x); o.y = f2b(v.y); o.z = f2b(v.z); o.w = f2b(v.w);
    ((ushort4*)Xbf)[i] = o;
  }
  for (size_t i = tid; i < 786432u; i += nth) {  // Wq|Wk|Wv
    int which = (int)(i >> 18);
    size_t off = i & 262143u;
    const float4* src = (const float4*)(which == 0 ? Wq : (which == 1 ? Wk : Wv));
    float4 v = src[off];
    ushort4 o; o.x = f2b(v.x); o.y = f2b(v.y); o.z = f2b(v.z); o.w = f2b(v.w);
    ((ushort4*)Wbf)[i] = o;
  }
  // relbits: coalesced — lane c reads int4, nibble-packs, 3x shfl_xor assembles
  const int4* r4 = (const int4*)rel;
  for (size_t c = tid; c < 8388608u; c += nth) {
    int4 v = r4[c];
    unsigned nib = (unsigned)(v.x == 1) | ((unsigned)(v.y == 1) << 1) |
                   ((unsigned)(v.z == 1) << 2) | ((unsigned)(v.w == 1) << 3);
    unsigned o1 = __shfl_xor((int)nib, 1);
    nib = (lane & 1) ? (o1 | (nib << 4)) : (nib | (o1 << 4));
    unsigned o2 = __shfl_xor((int)nib, 2);
    nib = (lane & 2) ? (o2 | (nib << 8)) : (nib | (o2 << 8));
    unsigned o4 = __shfl_xor((int)nib, 4);
    nib = (lane & 4) ? (o4 | (nib << 16)) : (nib | (o4 << 16));
    if ((lane & 7) == 0) bits[c >> 3] = nib;
  }
  for (size_t i = tid; i < 256u; i += nth) {  // dist_emb row 1
    float4 v = ((const float4*)(dist + H_LEN))[i];
    ushort4 o; o.x = f2b(v.x); o.y = f2b(v.y); o.z = f2b(v.z); o.w = f2b(v.w);
    ((ushort4*)de1)[i] = o;
  }
  for (size_t i = tid; i < 3072u; i += nth)
    b_all[i] = (i < 1024) ? bq[i] : (i < 2048 ? bk[i - 1024] : bv[i - 2048]);
  for (size_t i = tid; i < 32768u; i += nth) d1[i] = 0.f;  // d1 + denom
}

// ---------------- 256x256 NT-GEMM, BK=64 ------------------------------------
struct GArgs {
  const u16* A; const u16* B;
  long long sA, sB;
  int ldA, ldB, K;
  u16 *Qo, *Ko, *Vt; const float* b_all; const u16* de1; float* d1;       // EPI 0
  const unsigned* relbits; const float* mask; u16* P; float* denom;       // EPI 1
  float* outp;                                                            // EPI 2
};

template <int EPI>
__device__ __forceinline__ void gemm_body(GArgs g) {
  int bx, by, bz;
  {
    const int lin = blockIdx.x;
    if constexpr (EPI == 0) {        // 768 blocks: 96/XCD band swizzle (measured)
      const int wg = (lin & 7) * 96 + (lin >> 3);
      by = wg / 12; bx = wg % 12; bz = 0;
    } else if constexpr (EPI == 1) { // 512 blocks: batch-per-XCD (K-panel = 4MB
      const int wg = (lin & 7) * 64 + (lin >> 3);   //  = one XCD L2, resident)
      bz = wg >> 6; by = (wg >> 3) & 7; bx = wg & 7;
    } else {                         // 256 blocks: batch-per-XCD (measured good)
      const int wg = (lin & 7) * 32 + (lin >> 3);
      bz = wg >> 5; by = (wg >> 2) & 7; bx = wg & 3;
    }
  }
  const u16* Abase = g.A + (size_t)bz * g.sA;
  const u16* Bbase = g.B + (size_t)bz * g.sB;
  const int m0 = by * 256, n0 = bx * 256;

  __shared__ u16 smem[65536];  // 128 KiB: [buf0: A 32K|B 32K][buf1: A 32K|B 32K]

  const int tid = threadIdx.x;
  const int lane = tid & 63, w = tid >> 6;
  const int wm = w >> 2, wn = w & 3;          // 2 x 4 waves, wave tile 128 x 64
  const int l15 = lane & 15, quad = lane >> 4;

  f32x4 acc[8][4];
  const f32x4 zero = {0.f, 0.f, 0.f, 0.f};
#pragma unroll
  for (int a = 0; a < 8; ++a)
#pragma unroll
    for (int b = 0; b < 4; ++b) acc[a][b] = zero;

  // staging: LDS written linearly; global SOURCE pre-swizzled with the same XOR
  // used on ds_read (both-sides-or-neither rule)
  const u16* gA[4]; const u16* gB[4]; int qoff[4];
#pragma unroll
  for (int r = 0; r < 4; ++r) {
    const int q = r * 512 + tid;        // 16B-chunk id in [0,2048)
    const int row = q >> 3, ch = q & 7;
    const int chS = ch ^ (row & 7);
    gA[r] = Abase + (size_t)(m0 + row) * g.ldA + chS * 8;
    gB[r] = Bbase + (size_t)(n0 + row) * g.ldB + chS * 8;
    qoff[r] = q * 8;                    // u16 offset in tile
  }

  const int NT = g.K >> 6;

  auto stageFull = [&](int boff2, int kt) {
#pragma unroll
    for (int r = 0; r < 4; ++r) GLOAD16(gA[r] + kt, &smem[boff2 + qoff[r]]);
#pragma unroll
    for (int r = 0; r < 4; ++r) GLOAD16(gB[r] + kt, &smem[boff2 + 16384 + qoff[r]]);
  };
  auto stage2 = [&](int tile, int pr) {   // fine variant (EPI2 only)
    if (tile >= NT) return;
    const int boff2 = (tile & 1) << 15;
    const int kt = tile << 6;
    if (pr < 2) {
      GLOAD16(gA[2 * pr] + kt,     &smem[boff2 + qoff[2 * pr]]);
      GLOAD16(gA[2 * pr + 1] + kt, &smem[boff2 + qoff[2 * pr + 1]]);
    } else {
      const int r = 2 * (pr - 2);
      GLOAD16(gB[r] + kt,     &smem[boff2 + 16384 + qoff[r]]);
      GLOAD16(gB[r + 1] + kt, &smem[boff2 + 16384 + qoff[r + 1]]);
    }
  };

  bf16x8 af0[4][2], af1[4][2], bf0[2][2], bf1[2][2];

  if constexpr (EPI != 2) {
    // ======== coarse 4-phase loop (measured best for EPI0/EPI1) ============
    stageFull(0, 0);
    if (1 < NT) stageFull(32768, 64);
    WAIT_VM(8);
    PBAR();

    for (int t = 0; t < NT; ++t) {
      const int boff = (t & 1) << 15;
      const u16* Ab = smem + boff;
      const u16* Bb = smem + boff + 16384;

      // phase 0: read af0(8) + bf0(4); MFMA Q00
#pragma unroll
      for (int mt = 0; mt < 4; ++mt) {
        const int row = wm * 128 + mt * 16 + l15;
        const int base = row * 64, rx = row & 7;
        af0[mt][0] = *(const bf16x8*)&Ab[base + ((quad ^ rx) << 3)];
        af0[mt][1] = *(const bf16x8*)&Ab[base + (((quad + 4) ^ rx) << 3)];
      }
#pragma unroll
      for (int nt = 0; nt < 2; ++nt) {
        const int row = wn * 64 + nt * 16 + l15;
        const int base = row * 64, rx = row & 7;
        bf0[nt][0] = *(const bf16x8*)&Bb[base + ((quad ^ rx) << 3)];
        bf0[nt][1] = *(const bf16x8*)&Bb[base + (((quad + 4) ^ rx) << 3)];
      }
      asm volatile("s_waitcnt lgkmcnt(8)" ::: "memory");
      PBAR();
      WAIT_LGKM0();
      __builtin_amdgcn_s_setprio(1);
#pragma unroll
      for (int mt = 0; mt < 4; ++mt)
#pragma unroll
        for (int nt = 0; nt < 2; ++nt) {
          acc[mt][nt] = MM(af0[mt][0], bf0[nt][0], acc[mt][nt]);
          acc[mt][nt] = MM(af0[mt][1], bf0[nt][1], acc[mt][nt]);
        }
      __builtin_amdgcn_s_setprio(0);
      PBAR();

      // phase 1: read bf1(4); MFMA Q01
#pragma unroll
      for (int nt = 0; nt < 2; ++nt) {
        const int row = wn * 64 + (nt + 2) * 16 + l15;
        const int base = row * 64, rx = row & 7;
        bf1[nt][0] = *(const bf16x8*)&Bb[base + ((quad ^ rx) << 3)];
        bf1[nt][1] = *(const bf16x8*)&Bb[base + (((quad + 4) ^ rx) << 3)];
      }
      PBAR();
      WAIT_LGKM0();
      __builtin_amdgcn_s_setprio(1);
#pragma unroll
      for (int mt = 0; mt < 4; ++mt)
#pragma unroll
        for (int nt = 0; nt < 2; ++nt) {
          acc[mt][nt + 2] = MM(af0[mt][0], bf1[nt][0], acc[mt][nt + 2]);
          acc[mt][nt + 2] = MM(af0[mt][1], bf1[nt][1], acc[mt][nt + 2]);
        }
      __builtin_amdgcn_s_setprio(0);
      PBAR();

      // phase 2: read af1(8); MFMA Q10
#pragma unroll
      for (int mt = 0; mt < 4; ++mt) {
        const int row = wm * 128 + (mt + 4) * 16 + l15;
        const int base = row * 64, rx = row & 7;
        af1[mt][0] = *(const bf16x8*)&Ab[base + ((quad ^ rx) << 3)];
        af1[mt][1] = *(const bf16x8*)&Ab[base + (((quad + 4) ^ rx) << 3)];
      }
      PBAR();
      WAIT_LGKM0();
      __builtin_amdgcn_s_setprio(1);
#pragma unroll
      for (int mt = 0; mt < 4; ++mt)
#pragma unroll
        for (int nt = 0; nt < 2; ++nt) {
          acc[mt + 4][nt] = MM(af1[mt][0], bf0[nt][0], acc[mt + 4][nt]);
          acc[mt + 4][nt] = MM(af1[mt][1], bf0[nt][1], acc[mt + 4][nt]);
        }
      __builtin_amdgcn_s_setprio(0);
      PBAR();

      // phase 3: stage(t+2) burst into freed buffer; MFMA Q11; vmcnt(8)
      if (t + 2 < NT) stageFull(boff, (t + 2) << 6);
      PBAR();
      WAIT_LGKM0();
      __builtin_amdgcn_s_setprio(1);
#pragma unroll
      for (int mt = 0; mt < 4; ++mt)
#pragma unroll
        for (int nt = 0; nt < 2; ++nt) {
          acc[mt + 4][nt + 2] = MM(af1[mt][0], bf1[nt][0], acc[mt + 4][nt + 2]);
          acc[mt + 4][nt + 2] = MM(af1[mt][1], bf1[nt][1], acc[mt + 4][nt + 2]);
        }
      __builtin_amdgcn_s_setprio(0);
      if (t + 2 < NT) {
        WAIT_VM(8);
      } else if (t + 1 < NT) {
        WAIT_VM(0);
      }
      PBAR();
    }
  } else {
    // ======== fine-staged loop (EPI2 measured ~88 µs, frozen) ==============
    stage2(0, 0); stage2(0, 1); stage2(0, 2); stage2(0, 3);
    stage2(1, 0);
    if (1 < NT) { WAIT_VM(2); } else { WAIT_VM(0); }
    PBAR();

    for (int t = 0; t < NT; ++t) {
      const int boff = (t & 1) << 15;
      const u16* Ab = smem + boff;
      const u16* Bb = smem + boff + 16384;

#pragma unroll
      for (int mt = 0; mt < 4; ++mt) {
        const int row = wm * 128 + mt * 16 + l15;
        const int base = row * 64, rx = row & 7;
        af0[mt][0] = *(const bf16x8*)&Ab[base + ((quad ^ rx) << 3)];
        af0[mt][1] = *(const bf16x8*)&Ab[base + (((quad + 4) ^ rx) << 3)];
      }
#pragma unroll
      for (int nt = 0; nt < 2; ++nt) {
        const int row = wn * 64 + nt * 16 + l15;
        const int base = row * 64, rx = row & 7;
        bf0[nt][0] = *(const bf16x8*)&Bb[base + ((quad ^ rx) << 3)];
        bf0[nt][1] = *(const bf16x8*)&Bb[base + (((quad + 4) ^ rx) << 3)];
      }
      stage2(t + 1, 1);
      asm volatile("s_waitcnt lgkmcnt(8)" ::: "memory");
      PBAR();
      WAIT_LGKM0();
      __builtin_amdgcn_s_setprio(1);
#pragma unroll
      for (int mt = 0; mt < 4; ++mt)
#pragma unroll
        for (int nt = 0; nt < 2; ++nt) {
          acc[mt][nt] = MM(af0[mt][0], bf0[nt][0], acc[mt][nt]);
          acc[mt][nt] = MM(af0[mt][1], bf0[nt][1], acc[mt][nt]);
        }
      __builtin_amdgcn_s_setprio(0);
      PBAR();

#pragma unroll
      for (int nt = 0; nt < 2; ++nt) {
        const int row = wn * 64 + (nt + 2) * 16 + l15;
        const int base = row * 64, rx = row & 7;
        bf1[nt][0] = *(const bf16x8*)&Bb[base + ((quad ^ rx) << 3)];
        bf1[nt][1] = *(const bf16x8*)&Bb[base + (((quad + 4) ^ rx) << 3)];
      }
      stage2(t + 1, 2);
      PBAR();
      WAIT_LGKM0();
      __builtin_amdgcn_s_setprio(1);
#pragma unroll
      for (int mt = 0; mt < 4; ++mt)
#pragma unroll
        for (int nt = 0; nt < 2; ++nt) {
          acc[mt][nt + 2] = MM(af0[mt][0], bf1[nt][0], acc[mt][nt + 2]);
          acc[mt][nt + 2] = MM(af0[mt][1], bf1[nt][1], acc[mt][nt + 2]);
        }
      __builtin_amdgcn_s_setprio(0);
      PBAR();

#pragma unroll
      for (int mt = 0; mt < 4; ++mt) {
        const int row = wm * 128 + (mt + 4) * 16 + l15;
        const int base = row * 64, rx = row & 7;
        af1[mt][0] = *(const bf16x8*)&Ab[base + ((quad ^ rx) << 3)];
        af1[mt][1] = *(const bf16x8*)&Ab[base + (((quad + 4) ^ rx) << 3)];
      }
      stage2(t + 1, 3);
      PBAR();
      WAIT_LGKM0();
      __builtin_amdgcn_s_setprio(1);
#pragma unroll
      for (int mt = 0; mt < 4; ++mt)
#pragma unroll
        for (int nt = 0; nt < 2; ++nt) {
          acc[mt + 4][nt] = MM(af1[mt][0], bf0[nt][0], acc[mt + 4][nt]);
          acc[mt + 4][nt] = MM(af1[mt][1], bf0[nt][1], acc[mt + 4][nt]);
        }
      __builtin_amdgcn_s_setprio(0);
      PBAR();

      stage2(t + 2, 0);
      PBAR();
      WAIT_LGKM0();
      __builtin_amdgcn_s_setprio(1);
#pragma unroll
      for (int mt = 0; mt < 4; ++mt)
#pragma unroll
        for (int nt = 0; nt < 2; ++nt) {
          acc[mt + 4][nt + 2] = MM(af1[mt][0], bf1[nt][0], acc[mt + 4][nt + 2]);
          acc[mt + 4][nt + 2] = MM(af1[mt][1], bf1[nt][1], acc[mt + 4][nt + 2]);
        }
      __builtin_amdgcn_s_setprio(0);
      if (t + 2 < NT) {
        WAIT_VM(2);
      } else if (t + 1 < NT) {
        WAIT_VM(0);
      }
      PBAR();
    }
  }

  // C/D layout: col = lane&15, row = quad*4 + reg; thread rows: mt(8) x r(4)
  const int nbase = n0 + wn * 64;

  if constexpr (EPI == 0) {
    const int which = n0 >> 10;  // 0=Q, 1=K, 2=V — uniform per block
    const int nl0 = n0 & 1023;
    float bv4[4], dw[4];
#pragma unroll
    for (int nt = 0; nt < 4; ++nt) {
      const int col = wn * 64 + nt * 16 + l15;
      bv4[nt] = g.b_all[n0 + col];
      dw[nt] = (which == 0) ? b2f(g.de1[nl0 + col]) : 0.f;
    }
    if (which < 2) {  // Q / K: row-major bf16 store + fused d1 partial (Q)
#pragma unroll
      for (int mt = 0; mt < 8; ++mt)
#pragma unroll
        for (int r = 0; r < 4; ++r) {
          const int row = wm * 128 + mt * 16 + quad * 4 + r;
          float part = 0.f;
#pragma unroll
          for (int nt = 0; nt < 4; ++nt) {
            const float v = acc[mt][nt][r] + bv4[nt];
            part += v * dw[nt];
            const int col = wn * 64 + nt * 16 + l15;
            const int chS = (col >> 3) ^ (row & 31);
            smem[row * 256 + chS * 8 + (col & 7)] = f2b(v);
          }
          if (which == 0) {
            part += __shfl_xor(part, 1);
            part += __shfl_xor(part, 2);
            part += __shfl_xor(part, 4);
            part += __shfl_xor(part, 8);
            if (l15 == 0) atomicAdd(&g.d1[m0 + row], part);
          }
        }
      __syncthreads();
      u16* dstbuf = which == 0 ? g.Qo : g.Ko;
#pragma unroll
      for (int p = 0; p < 16; ++p) {
        const int flat = p * 512 + tid;
        const int row = flat >> 5, chunk = flat & 31;
        const int chS = chunk ^ (row & 31);
        u16x8 v = *(const u16x8*)&smem[row * 256 + chS * 8];
        *(u16x8*)(dstbuf + (size_t)(m0 + row) * H_LEN + nl0 + chunk * 8) = v;
      }
    } else {  // V: store tile TRANSPOSED in smem, write Vt[b][dim][seq] direct
#pragma unroll
      for (int mt = 0; mt < 8; ++mt)
#pragma unroll
        for (int r = 0; r < 4; ++r) {
          const int row = wm * 128 + mt * 16 + quad * 4 + r;  // seq-local
#pragma unroll
          for (int nt = 0; nt < 4; ++nt) {
            const float v = acc[mt][nt][r] + bv4[nt];
            const int col = wn * 64 + nt * 16 + l15;          // dim-local
            const int chS = (row >> 3) ^ (col & 31);
            smem[col * 256 + chS * 8 + (row & 7)] = f2b(v);
          }
        }
      __syncthreads();
      const int batch = m0 >> 11, sl0 = m0 & 2047;
#pragma unroll
      for (int p = 0; p < 16; ++p) {
        const int flat = p * 512 + tid;
        const int dimc = flat >> 5, chunk = flat & 31;        // chunk over seq
        const int chS = chunk ^ (dimc & 31);
        u16x8 v = *(const u16x8*)&smem[dimc * 256 + chS * 8];
        *(u16x8*)(g.Vt + ((size_t)batch * H_LEN + nl0 + dimc) * S_LEN + sl0 +
                  chunk * 8) = v;
      }
    }
  }

  if constexpr (EPI == 1) {  // scores: bitmask bias + exp, denom partial, P store
    float mk[4];
#pragma unroll
    for (int nt = 0; nt < 4; ++nt) mk[nt] = g.mask[bz * S_LEN + nbase + nt * 16 + l15];
    const size_t bSS = (size_t)bz * S_LEN * S_LEN;
    const int wbase = (n0 + wn * 64) >> 5;
#pragma unroll
    for (int mt = 0; mt < 8; ++mt)
#pragma unroll
      for (int r = 0; r < 4; ++r) {
        const int row = wm * 128 + mt * 16 + quad * 4 + r;
        const int gi = bz * S_LEN + m0 + row;
        const float d1v = g.d1[gi] * 0.03125f;
        const unsigned w0 = g.relbits[(size_t)gi * 64 + wbase];
        const unsigned w1 = g.relbits[(size_t)gi * 64 + wbase + 1];
        float dsum = 0.f;
#pragma unroll
        for (int nt = 0; nt < 4; ++nt) {
          const unsigned word = (nt & 2) ? w1 : w0;
          const int pos = (nt * 16 + l15) & 31;
          const float bias = ((word >> pos) & 1) ? d1v : 0.f;
          const float logit = acc[mt][nt][r] * 0.03125f + bias + mk[nt];
          const float pv = __expf(logit);  // logits bounded, no max-shift
          const u16 pb = f2b(pv);
          dsum += b2f(pb);  // denominator over the SAME bf16 values PV consumes
          const int col = wn * 64 + nt * 16 + l15;
          const int chS = (col >> 3) ^ (row & 31);
          smem[row * 256 + chS * 8 + (col & 7)] = pb;
        }
        dsum += __shfl_xor(dsum, 1);
        dsum += __shfl_xor(dsum, 2);
        dsum += __shfl_xor(dsum, 4);
        dsum += __shfl_xor(dsum, 8);
        if (l15 == 0) atomicAdd(&g.denom[gi], dsum);
      }
    __syncthreads();
#pragma unroll
    for (int p = 0; p < 16; ++p) {
      const int flat = p * 512 + tid;
      const int row = flat >> 5, chunk = flat & 31;
      const int chS = chunk ^ (row & 31);
      u16x8 v = *(const u16x8*)&smem[row * 256 + chS * 8];
      *(u16x8*)(g.P + bSS + (size_t)(m0 + row) * S_LEN + n0 + chunk * 8) = v;
    }
  }

  if constexpr (EPI == 2) {  // ctx: normalize by EPI1's denom, fp32 store
    const size_t ob = (size_t)bz * S_LEN * H_LEN;
#pragma unroll
    for (int mt = 0; mt < 8; ++mt)
#pragma unroll
      for (int r = 0; r < 4; ++r) {
        const int row = wm * 128 + mt * 16 + quad * 4 + r;
        const float inv = 1.0f / g.denom[bz * S_LEN + m0 + row];
        const size_t rowo = ob + (size_t)(m0 + row) * H_LEN;
#pragma unroll
        for (int nt = 0; nt < 4; ++nt)
          g.outp[rowo + nbase + nt * 16 + l15] = acc[mt][nt][r] * inv;
      }
  }
}

// Distinct kernel names so rocprof rows decompose the pipeline.
__global__ __launch_bounds__(512, 2) void gemm_qkv(GArgs g)    { gemm_body<0>(g); }
__global__ __launch_bounds__(512, 2) void gemm_scores(GArgs g) { gemm_body<1>(g); }
__global__ __launch_bounds__(512, 2) void gemm_ctx(GArgs g)    { gemm_body<2>(g); }

extern "C" void kernel_launch(void* const* d_in, const int* in_sizes, int n_in,
                              void* d_out, int out_size, void* d_ws, size_t ws_size,
                              hipStream_t stream) {
  (void)in_sizes; (void)n_in; (void)out_size; (void)ws_size;
  const float* X    = (const float*)d_in[0];
  const float* mask = (const float*)d_in[1];
  const int*   rel  = (const int*)d_in[2];
  const float* Wq   = (const float*)d_in[3];
  const float* bq   = (const float*)d_in[4];
  const float* Wk   = (const float*)d_in[5];
  const float* bk   = (const float*)d_in[6];
  const float* Wv   = (const float*)d_in[7];
  const float* bv   = (const float*)d_in[8];
  const float* dist = (const float*)d_in[9];
  float* out = (float*)d_out;

  char* p = (char*)d_ws;
  u16* Xbf = (u16*)p;      p += (size_t)16384 * 1024 * 2;
  u16* Wbf = (u16*)p;      p += (size_t)3072 * 1024 * 2;
  float* b_all = (float*)p; p += 3072 * 4;
  u16* de1 = (u16*)p;      p += 4096;
  u16* Qb = (u16*)p;       p += (size_t)16384 * 1024 * 2;
  u16* Kb = (u16*)p;       p += (size_t)16384 * 1024 * 2;
  u16* Vt = (u16*)p;       p += (size_t)16384 * 1024 * 2;
  float* d1 = (float*)p;   p += 16384 * 4;
  float* denom = (float*)p; p += 16384 * 4;   // zeroed together with d1 in prep
  unsigned* relbits = (unsigned*)p; p += (size_t)1048576 * 4;
  u16* P = (u16*)p;        p += (size_t)8 * 2048 * 2048 * 2;

  prep_kernel<<<2048, 256, 0, stream>>>(X, Wq, Wk, Wv, bq, bk, bv, dist, rel,
                                        Xbf, Wbf, b_all, de1, relbits, d1);

  GArgs g0 = {};
  g0.A = Xbf; g0.B = Wbf; g0.sA = 0; g0.sB = 0;
  g0.ldA = 1024; g0.ldB = 1024; g0.K = 1024;
  g0.Qo = Qb; g0.Ko = Kb; g0.Vt = Vt; g0.b_all = b_all; g0.de1 = de1; g0.d1 = d1;
  gemm_qkv<<<dim3(768, 1, 1), dim3(512, 1, 1), 0, stream>>>(g0);

  GArgs g1 = {};
  g1.A = Qb; g1.B = Kb; g1.sA = 2048LL * 1024; g1.sB = 2048LL * 1024;
  g1.ldA = 1024; g1.ldB = 1024; g1.K = 1024;
  g1.relbits = relbits; g1.d1 = d1; g1.mask = mask; g1.P = P; g1.denom = denom;
  gemm_scores<<<dim3(512, 1, 1), dim3(512, 1, 1), 0, stream>>>(g1);

  GArgs g2 = {};
  g2.A = P; g2.B = Vt; g2.sA = 2048LL * 2048; g2.sB = 1024LL * 2048;
  g2.ldA = 2048; g2.ldB = 2048; g2.K = 2048;
  g2.denom = denom; g2.outp = out;
  gemm_ctx<<<dim3(256, 1, 1), dim3(512, 1, 1), 0, stream>>>(g2);
}